// Round 16
// baseline (192.250 us; speedup 1.0000x reference)
//
#include <hip/hip_runtime.h>

#define N_CAT   100000
#define N_USERS 50000
#define DIM     64
#define N_RELM1 15
#define E_EDGES 1500000
#define NNZ_E   1500000

#define HPB   125           // heads per bucket
#define NB_H  800           // N_CAT / HPB
#define UPB   80            // users per bucket
#define NB_U  625           // N_USERS / UPB
#define NB_T  (NB_H + NB_U) // 1425
#define CAP8  3072          // shared payload slots in fused agg

#define NS_TILES 1563       // ceil(N_CAT/64)
#define GT_TILES 782        // ceil(N_USERS/64)

#define BIN_BLKS 256
#define BIN_CH   5860       // ceil(E_EDGES / BIN_BLKS)

#define NTL(p) __builtin_nontemporal_load(p)

__device__ __forceinline__ float sb2f(unsigned int v, int sh) {
    return (float)(int)(signed char)((v >> sh) & 0xFFu);
}

// K1: prep — normsq tile-matmul + int8 table (per-row scale) + gating + per-chunk hists
template <bool USE8>
__global__ void __launch_bounds__(256)
prep_kernel(const float* __restrict__ cat, const float* __restrict__ uemb,
            const float* __restrict__ weight,
            const int* __restrict__ head, const int* __restrict__ iu,
            float* __restrict__ normsq, unsigned int* __restrict__ cat8,
            float* __restrict__ scl,
            float* __restrict__ gfac, int* __restrict__ gcnt,
            int* __restrict__ cnts_cat, int* __restrict__ cnts_u0,
            int* __restrict__ cnts_u1) {
    __shared__ float smem[8320];
    int t = threadIdx.x;
    int lane = t & 63, wid = t >> 6;
    if (blockIdx.x < NS_TILES) {
        float* c2    = smem;          // 64*65 raw values
        float* w2t   = smem + 4160;   // 64*16 [d][r] of w^2
        float* nsqT  = smem + 5184;   // 16*64 [r][n]
        float* rinv  = smem + 6208;   // 64
        float* rmaxp = smem + 6272;   // 256
        int nbase = blockIdx.x * 64;
        int nclamp = min(64, N_CAT - nbase);
        const float4* cat4 = (const float4*)cat;
        for (int i = t; i < 1024; i += 256) {
            int d = i >> 4, r = i & 15;
            float w = (r < N_RELM1) ? weight[r * 64 + d] : 0.f;
            w2t[i] = w * w;
        }
        for (int i = t; i < 1024; i += 256) {
            int row = i >> 4, q = i & 15;
            float4 v4 = (row < nclamp) ? cat4[(size_t)(nbase + row) * 16 + q]
                                       : make_float4(0.f, 0.f, 0.f, 0.f);
            c2[row * 65 + q * 4 + 0] = v4.x;
            c2[row * 65 + q * 4 + 1] = v4.y;
            c2[row * 65 + q * 4 + 2] = v4.z;
            c2[row * 65 + q * 4 + 3] = v4.w;
        }
        __syncthreads();
        if (USE8) {
            {
                int row = t >> 2, part = t & 3;
                float m = 0.f;
#pragma unroll
                for (int d = part * 16; d < part * 16 + 16; ++d)
                    m = fmaxf(m, fabsf(c2[row * 65 + d]));
                rmaxp[t] = m;
            }
            __syncthreads();
            if (t < 64) {
                float m = fmaxf(fmaxf(rmaxp[4 * t], rmaxp[4 * t + 1]),
                                fmaxf(rmaxp[4 * t + 2], rmaxp[4 * t + 3]));
                rinv[t] = (m > 0.f) ? 127.f / m : 0.f;
                if (t < nclamp) scl[nbase + t] = (m > 0.f) ? m / 127.f : 0.f;
            }
            __syncthreads();
            for (int i = t; i < 1024; i += 256) {
                int row = i >> 4, q4 = i & 15;
                if (row < nclamp) {
                    float inv = rinv[row];
                    int d0 = q4 * 4;
                    unsigned int p = 0;
#pragma unroll
                    for (int k = 0; k < 4; ++k) {
                        int q = (int)rintf(c2[row * 65 + d0 + k] * inv);
                        p |= ((unsigned int)(q & 0xFF)) << (8 * k);
                    }
                    cat8[(size_t)(nbase + row) * 16 + q4] = p;
                }
            }
        }
        float a0 = 0, a1 = 0, a2 = 0, a3 = 0;
        int r0 = wid * 4;
#pragma unroll 8
        for (int d = 0; d < 64; ++d) {
            float c = c2[lane * 65 + d];
            float cc = c * c;
            float4 w4 = *(float4*)&w2t[d * 16 + r0];
            a0 += cc * w4.x; a1 += cc * w4.y; a2 += cc * w4.z; a3 += cc * w4.w;
        }
        nsqT[(r0 + 0) * 64 + lane] = a0;
        nsqT[(r0 + 1) * 64 + lane] = a1;
        nsqT[(r0 + 2) * 64 + lane] = a2;
        nsqT[(r0 + 3) * 64 + lane] = a3;
        __syncthreads();
        for (int i = t; i < nclamp * 15; i += 256) {
            int n = i / 15, r = i - n * 15;
            normsq[(size_t)(nbase + n) * 15 + r] = nsqT[r * 64 + n];
        }
    } else if (blockIdx.x < NS_TILES + GT_TILES) {
        float* ut  = smem;          // 64*65
        float* wt  = smem + 4160;   // 64*16 [d][r]
        float* wrT = smem + 5184;   // 16*64 [r][d]
        float* st  = smem + 6208;   // 64*16 scores
        float* pt  = smem + 7232;   // 64*16 probs
        int ub_ = (blockIdx.x - NS_TILES) * 64;
        int uclamp = min(64, N_USERS - ub_);
        const float4* ue4 = (const float4*)uemb;
        for (int i = t; i < 1024; i += 256) {
            int d = i >> 4, r = i & 15;
            float w = (r < N_RELM1) ? weight[r * 64 + d] : 0.f;
            wt[i] = w;
            wrT[r * 64 + d] = w;
        }
        for (int i = t; i < 1024; i += 256) {
            int row = i >> 4, q = i & 15;
            float4 v4 = (row < uclamp) ? ue4[(size_t)(ub_ + row) * 16 + q]
                                       : make_float4(0.f, 0.f, 0.f, 0.f);
            ut[row * 65 + q * 4 + 0] = v4.x;
            ut[row * 65 + q * 4 + 1] = v4.y;
            ut[row * 65 + q * 4 + 2] = v4.z;
            ut[row * 65 + q * 4 + 3] = v4.w;
        }
        __syncthreads();
        float a0 = 0, a1 = 0, a2 = 0, a3 = 0;
        int r0 = wid * 4;
#pragma unroll 8
        for (int d = 0; d < 64; ++d) {
            float c = ut[lane * 65 + d];
            float4 w4 = *(float4*)&wt[d * 16 + r0];
            a0 += c * w4.x; a1 += c * w4.y; a2 += c * w4.z; a3 += c * w4.w;
        }
        st[lane * 16 + r0 + 0] = a0;
        st[lane * 16 + r0 + 1] = a1;
        st[lane * 16 + r0 + 2] = a2;
        st[lane * 16 + r0 + 3] = a3;
        __syncthreads();
        if (wid == 0) {
            float mx = -1e30f;
            float pv[N_RELM1];
#pragma unroll
            for (int r = 0; r < N_RELM1; ++r) mx = fmaxf(mx, st[lane * 16 + r]);
            float Z = 0.f;
#pragma unroll
            for (int r = 0; r < N_RELM1; ++r) { pv[r] = __expf(st[lane * 16 + r] - mx); Z += pv[r]; }
            float inv = 1.f / Z;
#pragma unroll
            for (int r = 0; r < N_RELM1; ++r) pt[lane * 16 + r] = pv[r] * inv;
        }
        __syncthreads();
        for (int i = t; i < uclamp * 64; i += 256) {
            int u = i >> 6, d = i & 63;
            float g = 0.f;
#pragma unroll
            for (int r = 0; r < N_RELM1; ++r) g += pt[u * 16 + r] * wrT[r * 64 + d];
            gfac[(size_t)(ub_ + u) * 64 + d] = g;
        }
    } else {
        // per-chunk histograms, chunked exactly as binning
        int* ccnt = (int*)smem;        // 800
        int* cu0  = ccnt + NB_H;       // 640
        int* cu1  = cu0 + 640;         // 640
        for (int i = t; i < NB_H + 1280; i += 256) ccnt[i] = 0;
        __syncthreads();
        int hb = blockIdx.x - NS_TILES - GT_TILES;
        int c0 = hb * BIN_CH;
        int c1 = min(c0 + BIN_CH, E_EDGES);
        int hmid = c0 + BIN_CH / 2;
        for (int e = c0 + t; e < c1; e += 256) {
            atomicAdd(&ccnt[NTL(&head[e]) / HPB], 1);
            int ub = NTL(&iu[e]) / UPB;
            atomicAdd((e < hmid) ? &cu0[ub] : &cu1[ub], 1);
        }
        __syncthreads();
        for (int i = t; i < NB_H; i += 256) {
            int v = ccnt[i];
            cnts_cat[hb * NB_H + i] = v;
            if (v) atomicAdd(&gcnt[i], v);
        }
        for (int j = t; j < NB_U; j += 256) {
            int v0 = cu0[j], v1 = cu1[j];
            cnts_u0[hb * 640 + j] = v0;
            cnts_u1[hb * 640 + j] = v1;
            if (v0 + v1) atomicAdd(&gcnt[NB_H + j], v0 + v1);
        }
    }
}

// K2: wave-scan of bucket counts
__global__ void __launch_bounds__(1024)
bscan_kernel(const int* __restrict__ gcnt,
             int* __restrict__ hbase, int* __restrict__ ubase,
             int* __restrict__ cur) {
    __shared__ int wtot[16];
    int t = threadIdx.x, lane = t & 63, wv = t >> 6;
    int i0 = 2 * t, i1 = 2 * t + 1;
    int c0 = (i0 < NB_T) ? gcnt[i0] : 0;
    int c1 = (i1 < NB_T) ? gcnt[i1] : 0;
    int s = c0 + c1;
    int incl = s;
#pragma unroll
    for (int d = 1; d < 64; d <<= 1) {
        int v = __shfl_up(incl, d, 64);
        if (lane >= d) incl += v;
    }
    if (lane == 63) wtot[wv] = incl;
    __syncthreads();
    int woff = 0;
#pragma unroll
    for (int w = 0; w < 16; ++w) {
        int x = wtot[w];
        if (w < wv) woff += x;
    }
    int excl = woff + incl - s;
    if (i0 < NB_T) {
        if (i0 < NB_H) { hbase[i0] = excl; cur[i0] = excl; }
        else { int v = excl - E_EDGES; ubase[i0 - NB_H] = v; cur[i0] = v; }
    }
    int e1 = excl + c0;
    if (i1 < NB_T) {
        if (i1 < NB_H) { hbase[i1] = e1; cur[i1] = e1; }
        else { int v = e1 - E_EDGES; ubase[i1 - NB_H] = v; cur[i1] = v; }
    }
    if (t == 0) { hbase[NB_H] = E_EDGES; ubase[NB_U] = NNZ_E; }
}

// generic block exclusive scan (n <= 2048), 1024 threads
__device__ __forceinline__ void block_scan_excl(const int* __restrict__ cnt,
                                                int* __restrict__ lofs, int n,
                                                int* __restrict__ wtot) {
    __syncthreads();
    int t = threadIdx.x, lane = t & 63, wv = t >> 6;
    int i0 = 2 * t, i1 = i0 + 1;
    int a0 = (i0 < n) ? cnt[i0] : 0;
    int a1 = (i1 < n) ? cnt[i1] : 0;
    int s = a0 + a1, incl = s;
#pragma unroll
    for (int d = 1; d < 64; d <<= 1) {
        int v = __shfl_up(incl, d, 64);
        if (lane >= d) incl += v;
    }
    if (lane == 63) wtot[wv] = incl;
    __syncthreads();
    int woff = 0;
#pragma unroll
    for (int w = 0; w < 16; ++w) { int x = wtot[w]; if (w < wv) woff += x; }
    int excl = woff + incl - s;
    if (i0 < n) lofs[i0] = excl;
    if (i1 < n) lofs[i1] = excl + a0;
    __syncthreads();
}

// K3: binning — counts precomputed; user payload pre-scaled by scl[ic] when USE8
template <bool USE8>
__global__ void __launch_bounds__(1024)
binning_kernel(const int* __restrict__ head, const int* __restrict__ tail,
               const int* __restrict__ etype,
               const int* __restrict__ iu, const int* __restrict__ ic,
               const float* __restrict__ ival, const float* __restrict__ scl,
               const int* __restrict__ cnts_cat, const int* __restrict__ cnts_u0,
               const int* __restrict__ cnts_u1,
               int* __restrict__ cur,
               int* __restrict__ ebinned, unsigned long long* __restrict__ nbinned) {
    __shared__ int scnt[NB_H];
    __shared__ int lofs[NB_H];
    __shared__ int gbase[NB_H];
    __shared__ int wtot[16];
    __shared__ int stage[BIN_CH];
    __shared__ unsigned short sbk[BIN_CH];
    int t = threadIdx.x;
    int hb = blockIdx.x;
    int c0 = hb * BIN_CH;
    int c1 = min(c0 + BIN_CH, E_EDGES);

    // ---- CAT edges ----
    for (int i = t; i < NB_H; i += 1024) scnt[i] = NTL(&cnts_cat[hb * NB_H + i]);
    block_scan_excl(scnt, lofs, NB_H, wtot);
    for (int i = t; i < NB_H; i += 1024) {
        int c = scnt[i];
        gbase[i] = c ? atomicAdd(&cur[i], c) : 0;
    }
    __syncthreads();
    for (int i = t; i < NB_H; i += 1024) scnt[i] = 0;
    __syncthreads();
    for (int e = c0 + t; e < c1; e += 1024) {
        int h = NTL(&head[e]);
        int b = h / HPB;
        int r = atomicAdd(&scnt[b], 1);
        int slot = lofs[b] + r;
        stage[slot] = ((h - b * HPB) << 21) | (NTL(&tail[e]) << 4) | (NTL(&etype[e]) - 1);
        sbk[slot] = (unsigned short)b;
    }
    __syncthreads();
    int cn = c1 - c0;
    for (int s = t; s < cn; s += 1024) {
        int bk = sbk[s];
        ebinned[gbase[bk] + (s - lofs[bk])] = stage[s];
    }

    // ---- USER nnz: two half-chunks ----
    int2* stage2 = (int2*)stage;
    int2* nb2 = (int2*)nbinned;
#pragma unroll 1
    for (int half = 0; half < 2; ++half) {
        int h0 = c0 + half * (BIN_CH / 2);
        int h1 = min(h0 + BIN_CH / 2, E_EDGES);
        const int* crow = half ? cnts_u1 : cnts_u0;
        __syncthreads();
        for (int i = t; i < NB_U; i += 1024) scnt[i] = NTL(&crow[hb * 640 + i]);
        block_scan_excl(scnt, lofs, NB_U, wtot);
        for (int i = t; i < NB_U; i += 1024) {
            int c = scnt[i];
            gbase[i] = c ? atomicAdd(&cur[NB_H + i], c) : 0;
        }
        __syncthreads();
        for (int i = t; i < NB_U; i += 1024) scnt[i] = 0;
        __syncthreads();
        for (int e = h0 + t; e < h1; e += 1024) {
            int u = NTL(&iu[e]);
            int b = u / UPB;
            int r = atomicAdd(&scnt[b], 1);
            int slot = lofs[b] + r;
            int cix = NTL(&ic[e]);
            float v = NTL(&ival[e]);
            if (USE8) v *= scl[cix];
            stage2[slot] = make_int2(((u - b * UPB) << 17) | cix, __float_as_int(v));
            sbk[slot] = (unsigned short)b;
        }
        __syncthreads();
        int hn = h1 - h0;
        for (int s = t; s < hn; s += 1024) {
            int bk = sbk[s];
            nb2[gbase[bk] + (s - lofs[bk])] = stage2[s];
        }
    }
}

// K4: fused agg — blocks [0,NB_H): cat softmax-agg; [NB_H,NB_T): user agg
// int8 rows, oct-split gather (8 lanes/row, 8 edges per load instr)
template <bool USE8>
__global__ void __launch_bounds__(512)
fused_agg(const int* __restrict__ ebinned, const int* __restrict__ hbase,
          const unsigned long long* __restrict__ nbinned, const int* __restrict__ ubase,
          const float* __restrict__ normsq, const float* __restrict__ catf,
          const unsigned int* __restrict__ cat8, const float* __restrict__ scl,
          const float* __restrict__ weight,
          float* __restrict__ catagg, float* __restrict__ useragg) {
    __shared__ unsigned long long buf8[CAP8];
    __shared__ float4 wlds4[N_RELM1 * 16];
    __shared__ float hn[HPB * N_RELM1];
    __shared__ int cnt[HPB];
    __shared__ int ofs[HPB + 1];
    __shared__ unsigned int mxu[HPB];
    __shared__ float Zs[HPB];
    const float4* cfr = (const float4*)catf;
    const uint2* c8r2 = (const uint2*)cat8;
    int t = threadIdx.x;
    int wid = t >> 6, lane = t & 63;
    int qlane = lane & 15, qid = lane >> 4;
    int olane = lane & 7, oid = lane >> 3;

    if (blockIdx.x < NB_H) {
        int b = blockIdx.x;
        int s0 = hbase[b];
        int n = min(hbase[b + 1] - s0, CAP8);
        for (int i = t; i < N_RELM1 * 16; i += 512)
            wlds4[i] = ((const float4*)weight)[i];
        for (int i = t; i < HPB * N_RELM1; i += 512)
            hn[i] = normsq[(size_t)b * HPB * N_RELM1 + i];
        for (int i = t; i < HPB; i += 512) { cnt[i] = 0; mxu[i] = 0u; Zs[i] = 0.f; }
        __syncthreads();
        for (int i = t; i < n; i += 512)
            atomicAdd(&cnt[ebinned[s0 + i] >> 21], 1);
        __syncthreads();
        if (wid == 0) {
            int i0 = 2 * lane, i1 = 2 * lane + 1;
            int c0 = (i0 < HPB) ? cnt[i0] : 0;
            int c1 = (i1 < HPB) ? cnt[i1] : 0;
            int s = c0 + c1, incl = s;
#pragma unroll
            for (int d = 1; d < 64; d <<= 1) {
                int v = __shfl_up(incl, d, 64);
                if (lane >= d) incl += v;
            }
            int excl = incl - s;
            if (i0 <= HPB) ofs[i0] = excl;
            if (i1 <= HPB) ofs[i1] = excl + c0;
        }
        __syncthreads();
        for (int i = t; i < HPB; i += 512) cnt[i] = 0;
        __syncthreads();
        for (int i = t; i < n; i += 512) {
            int pk = ebinned[s0 + i];
            int hl = pk >> 21, tj = (pk >> 4) & 0x1FFFF, rj = pk & 15;
            float att = hn[hl * N_RELM1 + rj] * normsq[(size_t)tj * N_RELM1 + rj];
            int r = atomicAdd(&cnt[hl], 1);
            buf8[ofs[hl] + r] = ((unsigned long long)__float_as_uint(att) << 32) | (unsigned int)pk;
            atomicMax(&mxu[hl], __float_as_uint(att));
        }
        __syncthreads();
        // exp pass: Z += w; store w*scl[tj] (scl hoisted out of gather loop)
        for (int i = t; i < n; i += 512) {
            unsigned long long pay = buf8[i];
            int pk = (int)(unsigned int)pay;
            int hl = pk >> 21;
            float att = __uint_as_float((unsigned int)(pay >> 32));
            float w = __expf(att - __uint_as_float(mxu[hl]));
            float wstore = USE8 ? w * scl[(pk >> 4) & 0x1FFFF] : w;
            ((unsigned int*)buf8)[2 * i + 1] = __float_as_uint(wstore);
            atomicAdd(&Zs[hl], w);
        }
        __syncthreads();
        for (int hl = wid; hl < HPB; hl += 8) {
            int h = b * HPB + hl;
            int e0 = ofs[hl], e1 = ofs[hl + 1];
            float invZ = (e1 > e0) ? 1.f / Zs[hl] : 0.f;
            if (USE8) {
                // oct-split: 8 edges per instr, unroll 2 (16 edges/iter)
                float a0 = 0, a1 = 0, a2 = 0, a3 = 0, a4 = 0, a5 = 0, a6 = 0, a7 = 0;
                for (int j = e0; j < e1; j += 16) {
#pragma unroll
                    for (int k = 0; k < 2; ++k) {
                        int idx = j + k * 8 + oid;
                        bool ok = idx < e1;
                        idx = ok ? idx : e0;
                        unsigned long long pay = buf8[idx];
                        int pk = (int)(unsigned int)pay;
                        float ws = ok ? __uint_as_float((unsigned int)(pay >> 32)) : 0.f;
                        int tj = (pk >> 4) & 0x1FFFF, rj = pk & 15;
                        uint2 uv = c8r2[(size_t)tj * 8 + olane];
                        float4 wl0 = wlds4[rj * 16 + olane * 2];
                        float4 wl1 = wlds4[rj * 16 + olane * 2 + 1];
                        a0 += ws * sb2f(uv.x, 0)  * wl0.x;
                        a1 += ws * sb2f(uv.x, 8)  * wl0.y;
                        a2 += ws * sb2f(uv.x, 16) * wl0.z;
                        a3 += ws * sb2f(uv.x, 24) * wl0.w;
                        a4 += ws * sb2f(uv.y, 0)  * wl1.x;
                        a5 += ws * sb2f(uv.y, 8)  * wl1.y;
                        a6 += ws * sb2f(uv.y, 16) * wl1.z;
                        a7 += ws * sb2f(uv.y, 24) * wl1.w;
                    }
                }
#pragma unroll
                for (int d = 8; d <= 32; d <<= 1) {
                    a0 += __shfl_xor(a0, d, 64); a1 += __shfl_xor(a1, d, 64);
                    a2 += __shfl_xor(a2, d, 64); a3 += __shfl_xor(a3, d, 64);
                    a4 += __shfl_xor(a4, d, 64); a5 += __shfl_xor(a5, d, 64);
                    a6 += __shfl_xor(a6, d, 64); a7 += __shfl_xor(a7, d, 64);
                }
                if (oid == 0) {
                    ((float4*)catagg)[(size_t)h * 16 + olane * 2] =
                        make_float4(a0 * invZ, a1 * invZ, a2 * invZ, a3 * invZ);
                    ((float4*)catagg)[(size_t)h * 16 + olane * 2 + 1] =
                        make_float4(a4 * invZ, a5 * invZ, a6 * invZ, a7 * invZ);
                }
            } else {
                float ax = 0.f, ay = 0.f, az = 0.f, aw = 0.f;
                for (int j = e0; j < e1; j += 16) {
#pragma unroll
                    for (int k = 0; k < 4; ++k) {
                        int idx = j + k * 4 + qid;
                        bool ok = idx < e1;
                        idx = ok ? idx : e0;
                        unsigned long long pay = buf8[idx];
                        int pk = (int)(unsigned int)pay;
                        float w = ok ? __uint_as_float((unsigned int)(pay >> 32)) : 0.f;
                        int tj = (pk >> 4) & 0x1FFFF, rj = pk & 15;
                        float4 cv = cfr[(size_t)tj * 16 + qlane];
                        float4 wl = wlds4[rj * 16 + qlane];
                        ax += w * cv.x * wl.x;
                        ay += w * cv.y * wl.y;
                        az += w * cv.z * wl.z;
                        aw += w * cv.w * wl.w;
                    }
                }
                ax += __shfl_xor(ax, 16, 64); ax += __shfl_xor(ax, 32, 64);
                ay += __shfl_xor(ay, 16, 64); ay += __shfl_xor(ay, 32, 64);
                az += __shfl_xor(az, 16, 64); az += __shfl_xor(az, 32, 64);
                aw += __shfl_xor(aw, 16, 64); aw += __shfl_xor(aw, 32, 64);
                if (lane < 16)
                    ((float4*)catagg)[(size_t)h * 16 + qlane] =
                        make_float4(ax * invZ, ay * invZ, az * invZ, aw * invZ);
            }
        }
    } else {
        int ub = blockIdx.x - NB_H;
        int s0 = ubase[ub];
        int n = min(ubase[ub + 1] - s0, CAP8);
        for (int i = t; i < UPB; i += 512) cnt[i] = 0;
        __syncthreads();
        for (int i = t; i < n; i += 512)
            atomicAdd(&cnt[((unsigned int)nbinned[s0 + i]) >> 17], 1);
        __syncthreads();
        if (wid == 0) {
            int i0 = 2 * lane, i1 = 2 * lane + 1;
            int c0 = (i0 < UPB) ? cnt[i0] : 0;
            int c1 = (i1 < UPB) ? cnt[i1] : 0;
            int s = c0 + c1, incl = s;
#pragma unroll
            for (int d = 1; d < 64; d <<= 1) {
                int v = __shfl_up(incl, d, 64);
                if (lane >= d) incl += v;
            }
            int excl = incl - s;
            if (i0 <= UPB) ofs[i0] = excl;
            if (i1 <= UPB) ofs[i1] = excl + c0;
        }
        __syncthreads();
        for (int i = t; i < UPB; i += 512) cnt[i] = 0;
        __syncthreads();
        for (int i = t; i < n; i += 512) {
            unsigned long long pay = nbinned[s0 + i];
            int ul = ((unsigned int)pay) >> 17;
            int r = atomicAdd(&cnt[ul], 1);
            buf8[ofs[ul] + r] = pay;
        }
        __syncthreads();
        for (int ul = wid; ul < UPB; ul += 8) {
            int u = ub * UPB + ul;
            int e0 = ofs[ul], e1 = ofs[ul + 1];
            if (USE8) {
                // oct-split: 8 edges per instr, unroll 4 (32 edges/iter)
                float a0 = 0, a1 = 0, a2 = 0, a3 = 0, a4 = 0, a5 = 0, a6 = 0, a7 = 0;
                for (int j = e0; j < e1; j += 32) {
#pragma unroll
                    for (int k = 0; k < 4; ++k) {
                        int idx = j + k * 8 + oid;
                        bool ok = idx < e1;
                        idx = ok ? idx : e0;
                        unsigned long long pay = buf8[idx];
                        float vs = ok ? __uint_as_float((unsigned int)(pay >> 32)) : 0.f;
                        int c = (int)((unsigned int)pay & 0x1FFFFu);
                        uint2 uv = c8r2[(size_t)c * 8 + olane];
                        a0 += vs * sb2f(uv.x, 0);
                        a1 += vs * sb2f(uv.x, 8);
                        a2 += vs * sb2f(uv.x, 16);
                        a3 += vs * sb2f(uv.x, 24);
                        a4 += vs * sb2f(uv.y, 0);
                        a5 += vs * sb2f(uv.y, 8);
                        a6 += vs * sb2f(uv.y, 16);
                        a7 += vs * sb2f(uv.y, 24);
                    }
                }
#pragma unroll
                for (int d = 8; d <= 32; d <<= 1) {
                    a0 += __shfl_xor(a0, d, 64); a1 += __shfl_xor(a1, d, 64);
                    a2 += __shfl_xor(a2, d, 64); a3 += __shfl_xor(a3, d, 64);
                    a4 += __shfl_xor(a4, d, 64); a5 += __shfl_xor(a5, d, 64);
                    a6 += __shfl_xor(a6, d, 64); a7 += __shfl_xor(a7, d, 64);
                }
                if (oid == 0) {
                    float4 g0 = ((float4*)useragg)[(size_t)u * 16 + olane * 2];
                    float4 g1 = ((float4*)useragg)[(size_t)u * 16 + olane * 2 + 1];
                    ((float4*)useragg)[(size_t)u * 16 + olane * 2] =
                        make_float4(a0 * (1.f + g0.x), a1 * (1.f + g0.y),
                                    a2 * (1.f + g0.z), a3 * (1.f + g0.w));
                    ((float4*)useragg)[(size_t)u * 16 + olane * 2 + 1] =
                        make_float4(a4 * (1.f + g1.x), a5 * (1.f + g1.y),
                                    a6 * (1.f + g1.z), a7 * (1.f + g1.w));
                }
            } else {
                float ax = 0.f, ay = 0.f, az = 0.f, aw = 0.f;
                for (int j = e0; j < e1; j += 32) {
#pragma unroll
                    for (int k = 0; k < 8; ++k) {
                        int idx = j + k * 4 + qid;
                        bool ok = idx < e1;
                        idx = ok ? idx : e0;
                        unsigned long long pay = buf8[idx];
                        float v = ok ? __uint_as_float((unsigned int)(pay >> 32)) : 0.f;
                        int c = (int)((unsigned int)pay & 0x1FFFFu);
                        float4 cv = cfr[(size_t)c * 16 + qlane];
                        ax += v * cv.x;
                        ay += v * cv.y;
                        az += v * cv.z;
                        aw += v * cv.w;
                    }
                }
                ax += __shfl_xor(ax, 16, 64); ax += __shfl_xor(ax, 32, 64);
                ay += __shfl_xor(ay, 16, 64); ay += __shfl_xor(ay, 32, 64);
                az += __shfl_xor(az, 16, 64); az += __shfl_xor(az, 32, 64);
                aw += __shfl_xor(aw, 16, 64); aw += __shfl_xor(aw, 32, 64);
                if (lane < 16) {
                    float4 gf = ((float4*)useragg)[(size_t)u * 16 + qlane];
                    ((float4*)useragg)[(size_t)u * 16 + qlane] =
                        make_float4(ax * (1.f + gf.x), ay * (1.f + gf.y),
                                    az * (1.f + gf.z), aw * (1.f + gf.w));
                }
            }
        }
    }
}

extern "C" void kernel_launch(void* const* d_in, const int* in_sizes, int n_in,
                              void* d_out, int out_size, void* d_ws, size_t ws_size,
                              hipStream_t stream) {
    const float* cat    = (const float*)d_in[0];
    const float* uemb   = (const float*)d_in[1];
    const int*   eidx   = (const int*)d_in[2];
    const int*   etype  = (const int*)d_in[3];
    const int*   iidx   = (const int*)d_in[4];
    const float* ival   = (const float*)d_in[5];
    const float* weight = (const float*)d_in[6];

    float* catagg  = (float*)d_out;
    float* useragg = (float*)d_out + (size_t)N_CAT * DIM;

    // workspace layout (4-byte words)
    int* ws = (int*)d_ws;
    float* normsq   = (float*)ws;                              // [0, 1.5M)
    int*   ebinned  = ws + 1500000;                            // [1.5M, 3M)
    unsigned long long* nbinned = (unsigned long long*)(ws + 3000000); // [3M, 6M)
    int*   gcnt     = ws + 6000000;                            // 1425
    int*   hbase    = ws + 6001425;                            // 801
    int*   ubase    = ws + 6002226;                            // 626
    int*   cur      = ws + 6002852;                            // 1425
    unsigned int* cat8 = (unsigned int*)(ws + 6004278);        // 1.6M words = 6.4MB int8 table
    float* scl      = (float*)(ws + 6004278 + 1600000);        // 100K floats
    const size_t NEED8 = (size_t)(6004278 + 1600000 + 100000) * 4;
    bool use8 = ws_size >= NEED8;

    // per-chunk count matrices live in the (dead-until-fused_agg) catagg region
    int* dscr     = (int*)d_out;
    int* cnts_cat = dscr;                   // 256*800
    int* cnts_u0  = dscr + 256 * NB_H;      // 256*640
    int* cnts_u1  = cnts_u0 + 256 * 640;    // 256*640

    const int* head = eidx;
    const int* tail = eidx + E_EDGES;
    const int* iu   = iidx;
    const int* ic   = iidx + NNZ_E;

    hipMemsetAsync(gcnt, 0, (size_t)NB_T * sizeof(int), stream);

    if (use8) {
        prep_kernel<true><<<NS_TILES + GT_TILES + BIN_BLKS, 256, 0, stream>>>(
            cat, uemb, weight, head, iu, normsq, cat8, scl, useragg, gcnt,
            cnts_cat, cnts_u0, cnts_u1);
        bscan_kernel<<<1, 1024, 0, stream>>>(gcnt, hbase, ubase, cur);
        binning_kernel<true><<<BIN_BLKS, 1024, 0, stream>>>(
            head, tail, etype, iu, ic, ival, scl,
            cnts_cat, cnts_u0, cnts_u1, cur, ebinned, nbinned);
        fused_agg<true><<<NB_T, 512, 0, stream>>>(
            ebinned, hbase, nbinned, ubase, normsq, cat, cat8, scl, weight, catagg, useragg);
    } else {
        prep_kernel<false><<<NS_TILES + GT_TILES + BIN_BLKS, 256, 0, stream>>>(
            cat, uemb, weight, head, iu, normsq, cat8, scl, useragg, gcnt,
            cnts_cat, cnts_u0, cnts_u1);
        bscan_kernel<<<1, 1024, 0, stream>>>(gcnt, hbase, ubase, cur);
        binning_kernel<false><<<BIN_BLKS, 1024, 0, stream>>>(
            head, tail, etype, iu, ic, ival, scl,
            cnts_cat, cnts_u0, cnts_u1, cur, ebinned, nbinned);
        fused_agg<false><<<NB_T, 512, 0, stream>>>(
            ebinned, hbase, nbinned, ubase, normsq, cat, cat8, scl, weight, catagg, useragg);
    }
}

// Round 17
// 178.286 us; speedup vs baseline: 1.0783x; 1.0783x over previous
//
#include <hip/hip_runtime.h>

#define N_CAT   100000
#define N_USERS 50000
#define DIM     64
#define N_RELM1 15
#define E_EDGES 1500000
#define NNZ_E   1500000

#define HPB   125           // heads per bucket
#define NB_H  800           // N_CAT / HPB
#define UPB   80            // users per bucket
#define NB_U  625           // N_USERS / UPB
#define NB_T  (NB_H + NB_U) // 1425
#define CAP8  3072          // shared payload slots in fused agg

#define NS_TILES 1563       // ceil(N_CAT/64)
#define GT_TILES 782        // ceil(N_USERS/64)

#define BIN_BLKS 256
#define BIN_CH   5860       // ceil(E_EDGES / BIN_BLKS)

#define NTL(p) __builtin_nontemporal_load(p)

__device__ __forceinline__ float sb2f(unsigned int v, int sh) {
    return (float)(int)(signed char)((v >> sh) & 0xFFu);
}

// K1: prep — normsq tile-matmul + int8 table (per-row scale) + gating + per-chunk hists
template <bool USE8>
__global__ void __launch_bounds__(256)
prep_kernel(const float* __restrict__ cat, const float* __restrict__ uemb,
            const float* __restrict__ weight,
            const int* __restrict__ head, const int* __restrict__ iu,
            float* __restrict__ normsq, unsigned int* __restrict__ cat8,
            float* __restrict__ scl,
            float* __restrict__ gfac, int* __restrict__ gcnt,
            int* __restrict__ cnts_cat, int* __restrict__ cnts_u0,
            int* __restrict__ cnts_u1) {
    __shared__ float smem[8320];
    int t = threadIdx.x;
    int lane = t & 63, wid = t >> 6;
    if (blockIdx.x < NS_TILES) {
        float* c2    = smem;          // 64*65 raw values
        float* w2t   = smem + 4160;   // 64*16 [d][r] of w^2
        float* nsqT  = smem + 5184;   // 16*64 [r][n]
        float* rinv  = smem + 6208;   // 64
        float* rmaxp = smem + 6272;   // 256
        int nbase = blockIdx.x * 64;
        int nclamp = min(64, N_CAT - nbase);
        const float4* cat4 = (const float4*)cat;
        for (int i = t; i < 1024; i += 256) {
            int d = i >> 4, r = i & 15;
            float w = (r < N_RELM1) ? weight[r * 64 + d] : 0.f;
            w2t[i] = w * w;
        }
        for (int i = t; i < 1024; i += 256) {
            int row = i >> 4, q = i & 15;
            float4 v4 = (row < nclamp) ? cat4[(size_t)(nbase + row) * 16 + q]
                                       : make_float4(0.f, 0.f, 0.f, 0.f);
            c2[row * 65 + q * 4 + 0] = v4.x;
            c2[row * 65 + q * 4 + 1] = v4.y;
            c2[row * 65 + q * 4 + 2] = v4.z;
            c2[row * 65 + q * 4 + 3] = v4.w;
        }
        __syncthreads();
        if (USE8) {
            {
                int row = t >> 2, part = t & 3;
                float m = 0.f;
#pragma unroll
                for (int d = part * 16; d < part * 16 + 16; ++d)
                    m = fmaxf(m, fabsf(c2[row * 65 + d]));
                rmaxp[t] = m;
            }
            __syncthreads();
            if (t < 64) {
                float m = fmaxf(fmaxf(rmaxp[4 * t], rmaxp[4 * t + 1]),
                                fmaxf(rmaxp[4 * t + 2], rmaxp[4 * t + 3]));
                rinv[t] = (m > 0.f) ? 127.f / m : 0.f;
                if (t < nclamp) scl[nbase + t] = (m > 0.f) ? m / 127.f : 0.f;
            }
            __syncthreads();
            for (int i = t; i < 1024; i += 256) {
                int row = i >> 4, q4 = i & 15;
                if (row < nclamp) {
                    float inv = rinv[row];
                    int d0 = q4 * 4;
                    unsigned int p = 0;
#pragma unroll
                    for (int k = 0; k < 4; ++k) {
                        int q = (int)rintf(c2[row * 65 + d0 + k] * inv);
                        p |= ((unsigned int)(q & 0xFF)) << (8 * k);
                    }
                    cat8[(size_t)(nbase + row) * 16 + q4] = p;
                }
            }
        }
        float a0 = 0, a1 = 0, a2 = 0, a3 = 0;
        int r0 = wid * 4;
#pragma unroll 8
        for (int d = 0; d < 64; ++d) {
            float c = c2[lane * 65 + d];
            float cc = c * c;
            float4 w4 = *(float4*)&w2t[d * 16 + r0];
            a0 += cc * w4.x; a1 += cc * w4.y; a2 += cc * w4.z; a3 += cc * w4.w;
        }
        nsqT[(r0 + 0) * 64 + lane] = a0;
        nsqT[(r0 + 1) * 64 + lane] = a1;
        nsqT[(r0 + 2) * 64 + lane] = a2;
        nsqT[(r0 + 3) * 64 + lane] = a3;
        __syncthreads();
        for (int i = t; i < nclamp * 15; i += 256) {
            int n = i / 15, r = i - n * 15;
            normsq[(size_t)(nbase + n) * 15 + r] = nsqT[r * 64 + n];
        }
    } else if (blockIdx.x < NS_TILES + GT_TILES) {
        float* ut  = smem;          // 64*65
        float* wt  = smem + 4160;   // 64*16 [d][r]
        float* wrT = smem + 5184;   // 16*64 [r][d]
        float* st  = smem + 6208;   // 64*16 scores
        float* pt  = smem + 7232;   // 64*16 probs
        int ub_ = (blockIdx.x - NS_TILES) * 64;
        int uclamp = min(64, N_USERS - ub_);
        const float4* ue4 = (const float4*)uemb;
        for (int i = t; i < 1024; i += 256) {
            int d = i >> 4, r = i & 15;
            float w = (r < N_RELM1) ? weight[r * 64 + d] : 0.f;
            wt[i] = w;
            wrT[r * 64 + d] = w;
        }
        for (int i = t; i < 1024; i += 256) {
            int row = i >> 4, q = i & 15;
            float4 v4 = (row < uclamp) ? ue4[(size_t)(ub_ + row) * 16 + q]
                                       : make_float4(0.f, 0.f, 0.f, 0.f);
            ut[row * 65 + q * 4 + 0] = v4.x;
            ut[row * 65 + q * 4 + 1] = v4.y;
            ut[row * 65 + q * 4 + 2] = v4.z;
            ut[row * 65 + q * 4 + 3] = v4.w;
        }
        __syncthreads();
        float a0 = 0, a1 = 0, a2 = 0, a3 = 0;
        int r0 = wid * 4;
#pragma unroll 8
        for (int d = 0; d < 64; ++d) {
            float c = ut[lane * 65 + d];
            float4 w4 = *(float4*)&wt[d * 16 + r0];
            a0 += c * w4.x; a1 += c * w4.y; a2 += c * w4.z; a3 += c * w4.w;
        }
        st[lane * 16 + r0 + 0] = a0;
        st[lane * 16 + r0 + 1] = a1;
        st[lane * 16 + r0 + 2] = a2;
        st[lane * 16 + r0 + 3] = a3;
        __syncthreads();
        if (wid == 0) {
            float mx = -1e30f;
            float pv[N_RELM1];
#pragma unroll
            for (int r = 0; r < N_RELM1; ++r) mx = fmaxf(mx, st[lane * 16 + r]);
            float Z = 0.f;
#pragma unroll
            for (int r = 0; r < N_RELM1; ++r) { pv[r] = __expf(st[lane * 16 + r] - mx); Z += pv[r]; }
            float inv = 1.f / Z;
#pragma unroll
            for (int r = 0; r < N_RELM1; ++r) pt[lane * 16 + r] = pv[r] * inv;
        }
        __syncthreads();
        for (int i = t; i < uclamp * 64; i += 256) {
            int u = i >> 6, d = i & 63;
            float g = 0.f;
#pragma unroll
            for (int r = 0; r < N_RELM1; ++r) g += pt[u * 16 + r] * wrT[r * 64 + d];
            gfac[(size_t)(ub_ + u) * 64 + d] = g;
        }
    } else {
        // per-chunk histograms, chunked exactly as binning
        int* ccnt = (int*)smem;        // 800
        int* cu0  = ccnt + NB_H;       // 640
        int* cu1  = cu0 + 640;         // 640
        for (int i = t; i < NB_H + 1280; i += 256) ccnt[i] = 0;
        __syncthreads();
        int hb = blockIdx.x - NS_TILES - GT_TILES;
        int c0 = hb * BIN_CH;
        int c1 = min(c0 + BIN_CH, E_EDGES);
        int hmid = c0 + BIN_CH / 2;
        for (int e = c0 + t; e < c1; e += 256) {
            atomicAdd(&ccnt[NTL(&head[e]) / HPB], 1);
            int ub = NTL(&iu[e]) / UPB;
            atomicAdd((e < hmid) ? &cu0[ub] : &cu1[ub], 1);
        }
        __syncthreads();
        for (int i = t; i < NB_H; i += 256) {
            int v = ccnt[i];
            cnts_cat[hb * NB_H + i] = v;
            if (v) atomicAdd(&gcnt[i], v);
        }
        for (int j = t; j < NB_U; j += 256) {
            int v0 = cu0[j], v1 = cu1[j];
            cnts_u0[hb * 640 + j] = v0;
            cnts_u1[hb * 640 + j] = v1;
            if (v0 + v1) atomicAdd(&gcnt[NB_H + j], v0 + v1);
        }
    }
}

// K2: wave-scan of bucket counts
__global__ void __launch_bounds__(1024)
bscan_kernel(const int* __restrict__ gcnt,
             int* __restrict__ hbase, int* __restrict__ ubase,
             int* __restrict__ cur) {
    __shared__ int wtot[16];
    int t = threadIdx.x, lane = t & 63, wv = t >> 6;
    int i0 = 2 * t, i1 = 2 * t + 1;
    int c0 = (i0 < NB_T) ? gcnt[i0] : 0;
    int c1 = (i1 < NB_T) ? gcnt[i1] : 0;
    int s = c0 + c1;
    int incl = s;
#pragma unroll
    for (int d = 1; d < 64; d <<= 1) {
        int v = __shfl_up(incl, d, 64);
        if (lane >= d) incl += v;
    }
    if (lane == 63) wtot[wv] = incl;
    __syncthreads();
    int woff = 0;
#pragma unroll
    for (int w = 0; w < 16; ++w) {
        int x = wtot[w];
        if (w < wv) woff += x;
    }
    int excl = woff + incl - s;
    if (i0 < NB_T) {
        if (i0 < NB_H) { hbase[i0] = excl; cur[i0] = excl; }
        else { int v = excl - E_EDGES; ubase[i0 - NB_H] = v; cur[i0] = v; }
    }
    int e1 = excl + c0;
    if (i1 < NB_T) {
        if (i1 < NB_H) { hbase[i1] = e1; cur[i1] = e1; }
        else { int v = e1 - E_EDGES; ubase[i1 - NB_H] = v; cur[i1] = v; }
    }
    if (t == 0) { hbase[NB_H] = E_EDGES; ubase[NB_U] = NNZ_E; }
}

// generic block exclusive scan (n <= 2048), 1024 threads
__device__ __forceinline__ void block_scan_excl(const int* __restrict__ cnt,
                                                int* __restrict__ lofs, int n,
                                                int* __restrict__ wtot) {
    __syncthreads();
    int t = threadIdx.x, lane = t & 63, wv = t >> 6;
    int i0 = 2 * t, i1 = i0 + 1;
    int a0 = (i0 < n) ? cnt[i0] : 0;
    int a1 = (i1 < n) ? cnt[i1] : 0;
    int s = a0 + a1, incl = s;
#pragma unroll
    for (int d = 1; d < 64; d <<= 1) {
        int v = __shfl_up(incl, d, 64);
        if (lane >= d) incl += v;
    }
    if (lane == 63) wtot[wv] = incl;
    __syncthreads();
    int woff = 0;
#pragma unroll
    for (int w = 0; w < 16; ++w) { int x = wtot[w]; if (w < wv) woff += x; }
    int excl = woff + incl - s;
    if (i0 < n) lofs[i0] = excl;
    if (i1 < n) lofs[i1] = excl + a0;
    __syncthreads();
}

// K3: binning — counts precomputed; user payload pre-scaled by scl[ic] when USE8
template <bool USE8>
__global__ void __launch_bounds__(1024)
binning_kernel(const int* __restrict__ head, const int* __restrict__ tail,
               const int* __restrict__ etype,
               const int* __restrict__ iu, const int* __restrict__ ic,
               const float* __restrict__ ival, const float* __restrict__ scl,
               const int* __restrict__ cnts_cat, const int* __restrict__ cnts_u0,
               const int* __restrict__ cnts_u1,
               int* __restrict__ cur,
               int* __restrict__ ebinned, unsigned long long* __restrict__ nbinned) {
    __shared__ int scnt[NB_H];
    __shared__ int lofs[NB_H];
    __shared__ int gbase[NB_H];
    __shared__ int wtot[16];
    __shared__ int stage[BIN_CH];
    __shared__ unsigned short sbk[BIN_CH];
    int t = threadIdx.x;
    int hb = blockIdx.x;
    int c0 = hb * BIN_CH;
    int c1 = min(c0 + BIN_CH, E_EDGES);

    // ---- CAT edges ----
    for (int i = t; i < NB_H; i += 1024) scnt[i] = NTL(&cnts_cat[hb * NB_H + i]);
    block_scan_excl(scnt, lofs, NB_H, wtot);
    for (int i = t; i < NB_H; i += 1024) {
        int c = scnt[i];
        gbase[i] = c ? atomicAdd(&cur[i], c) : 0;
    }
    __syncthreads();
    for (int i = t; i < NB_H; i += 1024) scnt[i] = 0;
    __syncthreads();
    for (int e = c0 + t; e < c1; e += 1024) {
        int h = NTL(&head[e]);
        int b = h / HPB;
        int r = atomicAdd(&scnt[b], 1);
        int slot = lofs[b] + r;
        stage[slot] = ((h - b * HPB) << 21) | (NTL(&tail[e]) << 4) | (NTL(&etype[e]) - 1);
        sbk[slot] = (unsigned short)b;
    }
    __syncthreads();
    int cn = c1 - c0;
    for (int s = t; s < cn; s += 1024) {
        int bk = sbk[s];
        ebinned[gbase[bk] + (s - lofs[bk])] = stage[s];
    }

    // ---- USER nnz: two half-chunks ----
    int2* stage2 = (int2*)stage;
    int2* nb2 = (int2*)nbinned;
#pragma unroll 1
    for (int half = 0; half < 2; ++half) {
        int h0 = c0 + half * (BIN_CH / 2);
        int h1 = min(h0 + BIN_CH / 2, E_EDGES);
        const int* crow = half ? cnts_u1 : cnts_u0;
        __syncthreads();
        for (int i = t; i < NB_U; i += 1024) scnt[i] = NTL(&crow[hb * 640 + i]);
        block_scan_excl(scnt, lofs, NB_U, wtot);
        for (int i = t; i < NB_U; i += 1024) {
            int c = scnt[i];
            gbase[i] = c ? atomicAdd(&cur[NB_H + i], c) : 0;
        }
        __syncthreads();
        for (int i = t; i < NB_U; i += 1024) scnt[i] = 0;
        __syncthreads();
        for (int e = h0 + t; e < h1; e += 1024) {
            int u = NTL(&iu[e]);
            int b = u / UPB;
            int r = atomicAdd(&scnt[b], 1);
            int slot = lofs[b] + r;
            int cix = NTL(&ic[e]);
            float v = NTL(&ival[e]);
            if (USE8) v *= scl[cix];
            stage2[slot] = make_int2(((u - b * UPB) << 17) | cix, __float_as_int(v));
            sbk[slot] = (unsigned short)b;
        }
        __syncthreads();
        int hn = h1 - h0;
        for (int s = t; s < hn; s += 1024) {
            int bk = sbk[s];
            nb2[gbase[bk] + (s - lofs[bk])] = stage2[s];
        }
    }
}

// K4: fused agg — blocks [0,NB_H): cat softmax-agg; [NB_H,NB_T): user agg
// int8 rows + per-row scale hoisted out of gather loops; quarter-split gather
template <bool USE8>
__global__ void __launch_bounds__(512)
fused_agg(const int* __restrict__ ebinned, const int* __restrict__ hbase,
          const unsigned long long* __restrict__ nbinned, const int* __restrict__ ubase,
          const float* __restrict__ normsq, const float* __restrict__ catf,
          const unsigned int* __restrict__ cat8, const float* __restrict__ scl,
          const float* __restrict__ weight,
          float* __restrict__ catagg, float* __restrict__ useragg) {
    __shared__ unsigned long long buf8[CAP8];
    __shared__ float4 wlds4[N_RELM1 * 16];
    __shared__ float hn[HPB * N_RELM1];
    __shared__ int cnt[HPB];
    __shared__ int ofs[HPB + 1];
    __shared__ unsigned int mxu[HPB];
    __shared__ float Zs[HPB];
    const float4* cfr = (const float4*)catf;
    int t = threadIdx.x;
    int wid = t >> 6, lane = t & 63;
    int qlane = lane & 15, qid = lane >> 4;

    if (blockIdx.x < NB_H) {
        int b = blockIdx.x;
        int s0 = hbase[b];
        int n = min(hbase[b + 1] - s0, CAP8);
        for (int i = t; i < N_RELM1 * 16; i += 512)
            wlds4[i] = ((const float4*)weight)[i];
        for (int i = t; i < HPB * N_RELM1; i += 512)
            hn[i] = normsq[(size_t)b * HPB * N_RELM1 + i];
        for (int i = t; i < HPB; i += 512) { cnt[i] = 0; mxu[i] = 0u; Zs[i] = 0.f; }
        __syncthreads();
        for (int i = t; i < n; i += 512)
            atomicAdd(&cnt[ebinned[s0 + i] >> 21], 1);
        __syncthreads();
        if (wid == 0) {
            int i0 = 2 * lane, i1 = 2 * lane + 1;
            int c0 = (i0 < HPB) ? cnt[i0] : 0;
            int c1 = (i1 < HPB) ? cnt[i1] : 0;
            int s = c0 + c1, incl = s;
#pragma unroll
            for (int d = 1; d < 64; d <<= 1) {
                int v = __shfl_up(incl, d, 64);
                if (lane >= d) incl += v;
            }
            int excl = incl - s;
            if (i0 <= HPB) ofs[i0] = excl;
            if (i1 <= HPB) ofs[i1] = excl + c0;
        }
        __syncthreads();
        for (int i = t; i < HPB; i += 512) cnt[i] = 0;
        __syncthreads();
        for (int i = t; i < n; i += 512) {
            int pk = ebinned[s0 + i];
            int hl = pk >> 21, tj = (pk >> 4) & 0x1FFFF, rj = pk & 15;
            float att = hn[hl * N_RELM1 + rj] * normsq[(size_t)tj * N_RELM1 + rj];
            int r = atomicAdd(&cnt[hl], 1);
            buf8[ofs[hl] + r] = ((unsigned long long)__float_as_uint(att) << 32) | (unsigned int)pk;
            atomicMax(&mxu[hl], __float_as_uint(att));
        }
        __syncthreads();
        // exp pass: Z += w; store w*scl[tj] (scl hoisted out of gather loop)
        for (int i = t; i < n; i += 512) {
            unsigned long long pay = buf8[i];
            int pk = (int)(unsigned int)pay;
            int hl = pk >> 21;
            float att = __uint_as_float((unsigned int)(pay >> 32));
            float w = __expf(att - __uint_as_float(mxu[hl]));
            float wstore = USE8 ? w * scl[(pk >> 4) & 0x1FFFF] : w;
            ((unsigned int*)buf8)[2 * i + 1] = __float_as_uint(wstore);
            atomicAdd(&Zs[hl], w);
        }
        __syncthreads();
        // quarter-split gather, 4-deep (16 edges/iter)
        for (int hl = wid; hl < HPB; hl += 8) {
            int h = b * HPB + hl;
            int e0 = ofs[hl], e1 = ofs[hl + 1];
            float invZ = (e1 > e0) ? 1.f / Zs[hl] : 0.f;
            float ax = 0.f, ay = 0.f, az = 0.f, aw = 0.f;
            for (int j = e0; j < e1; j += 16) {
#pragma unroll
                for (int k = 0; k < 4; ++k) {
                    int idx = j + k * 4 + qid;
                    bool ok = idx < e1;
                    idx = ok ? idx : e0;
                    unsigned long long pay = buf8[idx];
                    int pk = (int)(unsigned int)pay;
                    float ws = ok ? __uint_as_float((unsigned int)(pay >> 32)) : 0.f;
                    int tj = (pk >> 4) & 0x1FFFF, rj = pk & 15;
                    float4 wl = wlds4[rj * 16 + qlane];
                    if (USE8) {
                        unsigned int uv = cat8[(size_t)tj * 16 + qlane];
                        ax += ws * sb2f(uv, 0)  * wl.x;
                        ay += ws * sb2f(uv, 8)  * wl.y;
                        az += ws * sb2f(uv, 16) * wl.z;
                        aw += ws * sb2f(uv, 24) * wl.w;
                    } else {
                        float4 cv = cfr[(size_t)tj * 16 + qlane];
                        ax += ws * cv.x * wl.x;
                        ay += ws * cv.y * wl.y;
                        az += ws * cv.z * wl.z;
                        aw += ws * cv.w * wl.w;
                    }
                }
            }
            ax += __shfl_xor(ax, 16, 64); ax += __shfl_xor(ax, 32, 64);
            ay += __shfl_xor(ay, 16, 64); ay += __shfl_xor(ay, 32, 64);
            az += __shfl_xor(az, 16, 64); az += __shfl_xor(az, 32, 64);
            aw += __shfl_xor(aw, 16, 64); aw += __shfl_xor(aw, 32, 64);
            if (lane < 16)
                ((float4*)catagg)[(size_t)h * 16 + qlane] =
                    make_float4(ax * invZ, ay * invZ, az * invZ, aw * invZ);
        }
    } else {
        int ub = blockIdx.x - NB_H;
        int s0 = ubase[ub];
        int n = min(ubase[ub + 1] - s0, CAP8);
        for (int i = t; i < UPB; i += 512) cnt[i] = 0;
        __syncthreads();
        for (int i = t; i < n; i += 512)
            atomicAdd(&cnt[((unsigned int)nbinned[s0 + i]) >> 17], 1);
        __syncthreads();
        if (wid == 0) {
            int i0 = 2 * lane, i1 = 2 * lane + 1;
            int c0 = (i0 < UPB) ? cnt[i0] : 0;
            int c1 = (i1 < UPB) ? cnt[i1] : 0;
            int s = c0 + c1, incl = s;
#pragma unroll
            for (int d = 1; d < 64; d <<= 1) {
                int v = __shfl_up(incl, d, 64);
                if (lane >= d) incl += v;
            }
            int excl = incl - s;
            if (i0 <= UPB) ofs[i0] = excl;
            if (i1 <= UPB) ofs[i1] = excl + c0;
        }
        __syncthreads();
        for (int i = t; i < UPB; i += 512) cnt[i] = 0;
        __syncthreads();
        for (int i = t; i < n; i += 512) {
            unsigned long long pay = nbinned[s0 + i];
            int ul = ((unsigned int)pay) >> 17;
            int r = atomicAdd(&cnt[ul], 1);
            buf8[ofs[ul] + r] = pay;
        }
        __syncthreads();
        // quarter-split gather, 8-deep (32 edges/iter); payload value pre-scaled
        for (int ul = wid; ul < UPB; ul += 8) {
            int u = ub * UPB + ul;
            int e0 = ofs[ul], e1 = ofs[ul + 1];
            float ax = 0.f, ay = 0.f, az = 0.f, aw = 0.f;
            for (int j = e0; j < e1; j += 32) {
#pragma unroll
                for (int k = 0; k < 8; ++k) {
                    int idx = j + k * 4 + qid;
                    bool ok = idx < e1;
                    idx = ok ? idx : e0;
                    unsigned long long pay = buf8[idx];
                    float vs = ok ? __uint_as_float((unsigned int)(pay >> 32)) : 0.f;
                    int c = (int)((unsigned int)pay & 0x1FFFFu);
                    if (USE8) {
                        unsigned int uv = cat8[(size_t)c * 16 + qlane];
                        ax += vs * sb2f(uv, 0);
                        ay += vs * sb2f(uv, 8);
                        az += vs * sb2f(uv, 16);
                        aw += vs * sb2f(uv, 24);
                    } else {
                        float4 cv = cfr[(size_t)c * 16 + qlane];
                        ax += vs * cv.x;
                        ay += vs * cv.y;
                        az += vs * cv.z;
                        aw += vs * cv.w;
                    }
                }
            }
            ax += __shfl_xor(ax, 16, 64); ax += __shfl_xor(ax, 32, 64);
            ay += __shfl_xor(ay, 16, 64); ay += __shfl_xor(ay, 32, 64);
            az += __shfl_xor(az, 16, 64); az += __shfl_xor(az, 32, 64);
            aw += __shfl_xor(aw, 16, 64); aw += __shfl_xor(aw, 32, 64);
            if (lane < 16) {
                float4 gf = ((float4*)useragg)[(size_t)u * 16 + qlane];
                ((float4*)useragg)[(size_t)u * 16 + qlane] =
                    make_float4(ax * (1.f + gf.x), ay * (1.f + gf.y),
                                az * (1.f + gf.z), aw * (1.f + gf.w));
            }
        }
    }
}

extern "C" void kernel_launch(void* const* d_in, const int* in_sizes, int n_in,
                              void* d_out, int out_size, void* d_ws, size_t ws_size,
                              hipStream_t stream) {
    const float* cat    = (const float*)d_in[0];
    const float* uemb   = (const float*)d_in[1];
    const int*   eidx   = (const int*)d_in[2];
    const int*   etype  = (const int*)d_in[3];
    const int*   iidx   = (const int*)d_in[4];
    const float* ival   = (const float*)d_in[5];
    const float* weight = (const float*)d_in[6];

    float* catagg  = (float*)d_out;
    float* useragg = (float*)d_out + (size_t)N_CAT * DIM;

    // workspace layout (4-byte words)
    int* ws = (int*)d_ws;
    float* normsq   = (float*)ws;                              // [0, 1.5M)
    int*   ebinned  = ws + 1500000;                            // [1.5M, 3M)
    unsigned long long* nbinned = (unsigned long long*)(ws + 3000000); // [3M, 6M)
    int*   gcnt     = ws + 6000000;                            // 1425
    int*   hbase    = ws + 6001425;                            // 801
    int*   ubase    = ws + 6002226;                            // 626
    int*   cur      = ws + 6002852;                            // 1425
    unsigned int* cat8 = (unsigned int*)(ws + 6004278);        // 1.6M words = 6.4MB int8 table
    float* scl      = (float*)(ws + 6004278 + 1600000);        // 100K floats
    const size_t NEED8 = (size_t)(6004278 + 1600000 + 100000) * 4;
    bool use8 = ws_size >= NEED8;

    // per-chunk count matrices live in the (dead-until-fused_agg) catagg region
    int* dscr     = (int*)d_out;
    int* cnts_cat = dscr;                   // 256*800
    int* cnts_u0  = dscr + 256 * NB_H;      // 256*640
    int* cnts_u1  = cnts_u0 + 256 * 640;    // 256*640

    const int* head = eidx;
    const int* tail = eidx + E_EDGES;
    const int* iu   = iidx;
    const int* ic   = iidx + NNZ_E;

    hipMemsetAsync(gcnt, 0, (size_t)NB_T * sizeof(int), stream);

    if (use8) {
        prep_kernel<true><<<NS_TILES + GT_TILES + BIN_BLKS, 256, 0, stream>>>(
            cat, uemb, weight, head, iu, normsq, cat8, scl, useragg, gcnt,
            cnts_cat, cnts_u0, cnts_u1);
        bscan_kernel<<<1, 1024, 0, stream>>>(gcnt, hbase, ubase, cur);
        binning_kernel<true><<<BIN_BLKS, 1024, 0, stream>>>(
            head, tail, etype, iu, ic, ival, scl,
            cnts_cat, cnts_u0, cnts_u1, cur, ebinned, nbinned);
        fused_agg<true><<<NB_T, 512, 0, stream>>>(
            ebinned, hbase, nbinned, ubase, normsq, cat, cat8, scl, weight, catagg, useragg);
    } else {
        prep_kernel<false><<<NS_TILES + GT_TILES + BIN_BLKS, 256, 0, stream>>>(
            cat, uemb, weight, head, iu, normsq, cat8, scl, useragg, gcnt,
            cnts_cat, cnts_u0, cnts_u1);
        bscan_kernel<<<1, 1024, 0, stream>>>(gcnt, hbase, ubase, cur);
        binning_kernel<false><<<BIN_BLKS, 1024, 0, stream>>>(
            head, tail, etype, iu, ic, ival, scl,
            cnts_cat, cnts_u0, cnts_u1, cur, ebinned, nbinned);
        fused_agg<false><<<NB_T, 512, 0, stream>>>(
            ebinned, hbase, nbinned, ubase, normsq, cat, cat8, scl, weight, catagg, useragg);
    }
}

// Round 18
// 170.851 us; speedup vs baseline: 1.1253x; 1.0435x over previous
//
#include <hip/hip_runtime.h>
#include <hip/hip_fp16.h>

#define N_CAT   100000
#define N_USERS 50000
#define DIM     64
#define N_RELM1 15
#define E_EDGES 1500000
#define NNZ_E   1500000

#define HPB   125           // heads per bucket
#define NB_H  800           // N_CAT / HPB
#define UPB   80            // users per bucket
#define NB_U  625           // N_USERS / UPB
#define NB_T  (NB_H + NB_U) // 1425
#define CAP8  3072          // shared payload slots in fused agg

#define NS_TILES 1563       // ceil(N_CAT/64)
#define GT_TILES 782        // ceil(N_USERS/64)

#define BIN_BLKS 256
#define BIN_CH   5860       // ceil(E_EDGES / BIN_BLKS)

#define NTL(p) __builtin_nontemporal_load(p)

__device__ __forceinline__ float sb2f(unsigned int v, int sh) {
    return (float)(int)(signed char)((v >> sh) & 0xFFu);
}

// K1: prep — f16 normsq tile-matmul + int8 table (per-row scale) + gating + per-chunk hists
template <bool USE8>
__global__ void __launch_bounds__(256)
prep_kernel(const float* __restrict__ cat, const float* __restrict__ uemb,
            const float* __restrict__ weight,
            const int* __restrict__ head, const int* __restrict__ iu,
            __half* __restrict__ normsq16, unsigned int* __restrict__ cat8,
            float* __restrict__ scl,
            float* __restrict__ gfac, int* __restrict__ gcnt,
            int* __restrict__ cnts_cat, int* __restrict__ cnts_u0,
            int* __restrict__ cnts_u1) {
    __shared__ float smem[8320];
    int t = threadIdx.x;
    int lane = t & 63, wid = t >> 6;
    if (blockIdx.x < NS_TILES) {
        float* c2    = smem;          // 64*65 raw values
        float* w2t   = smem + 4160;   // 64*16 [d][r] of w^2
        float* nsqT  = smem + 5184;   // 16*64 [r][n]
        float* rinv  = smem + 6208;   // 64
        float* rmaxp = smem + 6272;   // 256
        int nbase = blockIdx.x * 64;
        int nclamp = min(64, N_CAT - nbase);
        const float4* cat4 = (const float4*)cat;
        for (int i = t; i < 1024; i += 256) {
            int d = i >> 4, r = i & 15;
            float w = (r < N_RELM1) ? weight[r * 64 + d] : 0.f;
            w2t[i] = w * w;
        }
        for (int i = t; i < 1024; i += 256) {
            int row = i >> 4, q = i & 15;
            float4 v4 = (row < nclamp) ? cat4[(size_t)(nbase + row) * 16 + q]
                                       : make_float4(0.f, 0.f, 0.f, 0.f);
            c2[row * 65 + q * 4 + 0] = v4.x;
            c2[row * 65 + q * 4 + 1] = v4.y;
            c2[row * 65 + q * 4 + 2] = v4.z;
            c2[row * 65 + q * 4 + 3] = v4.w;
        }
        __syncthreads();
        if (USE8) {
            {
                int row = t >> 2, part = t & 3;
                float m = 0.f;
#pragma unroll
                for (int d = part * 16; d < part * 16 + 16; ++d)
                    m = fmaxf(m, fabsf(c2[row * 65 + d]));
                rmaxp[t] = m;
            }
            __syncthreads();
            if (t < 64) {
                float m = fmaxf(fmaxf(rmaxp[4 * t], rmaxp[4 * t + 1]),
                                fmaxf(rmaxp[4 * t + 2], rmaxp[4 * t + 3]));
                rinv[t] = (m > 0.f) ? 127.f / m : 0.f;
                if (t < nclamp) scl[nbase + t] = (m > 0.f) ? m / 127.f : 0.f;
            }
            __syncthreads();
            for (int i = t; i < 1024; i += 256) {
                int row = i >> 4, q4 = i & 15;
                if (row < nclamp) {
                    float inv = rinv[row];
                    int d0 = q4 * 4;
                    unsigned int p = 0;
#pragma unroll
                    for (int k = 0; k < 4; ++k) {
                        int q = (int)rintf(c2[row * 65 + d0 + k] * inv);
                        p |= ((unsigned int)(q & 0xFF)) << (8 * k);
                    }
                    cat8[(size_t)(nbase + row) * 16 + q4] = p;
                }
            }
        }
        float a0 = 0, a1 = 0, a2 = 0, a3 = 0;
        int r0 = wid * 4;
#pragma unroll 8
        for (int d = 0; d < 64; ++d) {
            float c = c2[lane * 65 + d];
            float cc = c * c;
            float4 w4 = *(float4*)&w2t[d * 16 + r0];
            a0 += cc * w4.x; a1 += cc * w4.y; a2 += cc * w4.z; a3 += cc * w4.w;
        }
        nsqT[(r0 + 0) * 64 + lane] = a0;
        nsqT[(r0 + 1) * 64 + lane] = a1;
        nsqT[(r0 + 2) * 64 + lane] = a2;
        nsqT[(r0 + 3) * 64 + lane] = a3;
        __syncthreads();
        for (int i = t; i < nclamp * 15; i += 256) {
            int n = i / 15, r = i - n * 15;
            normsq16[(size_t)(nbase + n) * 15 + r] = __float2half(nsqT[r * 64 + n]);
        }
    } else if (blockIdx.x < NS_TILES + GT_TILES) {
        float* ut  = smem;          // 64*65
        float* wt  = smem + 4160;   // 64*16 [d][r]
        float* wrT = smem + 5184;   // 16*64 [r][d]
        float* st  = smem + 6208;   // 64*16 scores
        float* pt  = smem + 7232;   // 64*16 probs
        int ub_ = (blockIdx.x - NS_TILES) * 64;
        int uclamp = min(64, N_USERS - ub_);
        const float4* ue4 = (const float4*)uemb;
        for (int i = t; i < 1024; i += 256) {
            int d = i >> 4, r = i & 15;
            float w = (r < N_RELM1) ? weight[r * 64 + d] : 0.f;
            wt[i] = w;
            wrT[r * 64 + d] = w;
        }
        for (int i = t; i < 1024; i += 256) {
            int row = i >> 4, q = i & 15;
            float4 v4 = (row < uclamp) ? ue4[(size_t)(ub_ + row) * 16 + q]
                                       : make_float4(0.f, 0.f, 0.f, 0.f);
            ut[row * 65 + q * 4 + 0] = v4.x;
            ut[row * 65 + q * 4 + 1] = v4.y;
            ut[row * 65 + q * 4 + 2] = v4.z;
            ut[row * 65 + q * 4 + 3] = v4.w;
        }
        __syncthreads();
        float a0 = 0, a1 = 0, a2 = 0, a3 = 0;
        int r0 = wid * 4;
#pragma unroll 8
        for (int d = 0; d < 64; ++d) {
            float c = ut[lane * 65 + d];
            float4 w4 = *(float4*)&wt[d * 16 + r0];
            a0 += c * w4.x; a1 += c * w4.y; a2 += c * w4.z; a3 += c * w4.w;
        }
        st[lane * 16 + r0 + 0] = a0;
        st[lane * 16 + r0 + 1] = a1;
        st[lane * 16 + r0 + 2] = a2;
        st[lane * 16 + r0 + 3] = a3;
        __syncthreads();
        if (wid == 0) {
            float mx = -1e30f;
            float pv[N_RELM1];
#pragma unroll
            for (int r = 0; r < N_RELM1; ++r) mx = fmaxf(mx, st[lane * 16 + r]);
            float Z = 0.f;
#pragma unroll
            for (int r = 0; r < N_RELM1; ++r) { pv[r] = __expf(st[lane * 16 + r] - mx); Z += pv[r]; }
            float inv = 1.f / Z;
#pragma unroll
            for (int r = 0; r < N_RELM1; ++r) pt[lane * 16 + r] = pv[r] * inv;
        }
        __syncthreads();
        for (int i = t; i < uclamp * 64; i += 256) {
            int u = i >> 6, d = i & 63;
            float g = 0.f;
#pragma unroll
            for (int r = 0; r < N_RELM1; ++r) g += pt[u * 16 + r] * wrT[r * 64 + d];
            gfac[(size_t)(ub_ + u) * 64 + d] = g;
        }
    } else {
        // per-chunk histograms, chunked exactly as binning
        int* ccnt = (int*)smem;        // 800
        int* cu0  = ccnt + NB_H;       // 640
        int* cu1  = cu0 + 640;         // 640
        for (int i = t; i < NB_H + 1280; i += 256) ccnt[i] = 0;
        __syncthreads();
        int hb = blockIdx.x - NS_TILES - GT_TILES;
        int c0 = hb * BIN_CH;
        int c1 = min(c0 + BIN_CH, E_EDGES);
        int hmid = c0 + BIN_CH / 2;
        for (int e = c0 + t; e < c1; e += 256) {
            atomicAdd(&ccnt[NTL(&head[e]) / HPB], 1);
            int ub = NTL(&iu[e]) / UPB;
            atomicAdd((e < hmid) ? &cu0[ub] : &cu1[ub], 1);
        }
        __syncthreads();
        for (int i = t; i < NB_H; i += 256) {
            int v = ccnt[i];
            cnts_cat[hb * NB_H + i] = v;
            if (v) atomicAdd(&gcnt[i], v);
        }
        for (int j = t; j < NB_U; j += 256) {
            int v0 = cu0[j], v1 = cu1[j];
            cnts_u0[hb * 640 + j] = v0;
            cnts_u1[hb * 640 + j] = v1;
            if (v0 + v1) atomicAdd(&gcnt[NB_H + j], v0 + v1);
        }
    }
}

// K2: wave-scan of bucket counts
__global__ void __launch_bounds__(1024)
bscan_kernel(const int* __restrict__ gcnt,
             int* __restrict__ hbase, int* __restrict__ ubase,
             int* __restrict__ cur) {
    __shared__ int wtot[16];
    int t = threadIdx.x, lane = t & 63, wv = t >> 6;
    int i0 = 2 * t, i1 = 2 * t + 1;
    int c0 = (i0 < NB_T) ? gcnt[i0] : 0;
    int c1 = (i1 < NB_T) ? gcnt[i1] : 0;
    int s = c0 + c1;
    int incl = s;
#pragma unroll
    for (int d = 1; d < 64; d <<= 1) {
        int v = __shfl_up(incl, d, 64);
        if (lane >= d) incl += v;
    }
    if (lane == 63) wtot[wv] = incl;
    __syncthreads();
    int woff = 0;
#pragma unroll
    for (int w = 0; w < 16; ++w) {
        int x = wtot[w];
        if (w < wv) woff += x;
    }
    int excl = woff + incl - s;
    if (i0 < NB_T) {
        if (i0 < NB_H) { hbase[i0] = excl; cur[i0] = excl; }
        else { int v = excl - E_EDGES; ubase[i0 - NB_H] = v; cur[i0] = v; }
    }
    int e1 = excl + c0;
    if (i1 < NB_T) {
        if (i1 < NB_H) { hbase[i1] = e1; cur[i1] = e1; }
        else { int v = e1 - E_EDGES; ubase[i1 - NB_H] = v; cur[i1] = v; }
    }
    if (t == 0) { hbase[NB_H] = E_EDGES; ubase[NB_U] = NNZ_E; }
}

// generic block exclusive scan (n <= 2048), 1024 threads
__device__ __forceinline__ void block_scan_excl(const int* __restrict__ cnt,
                                                int* __restrict__ lofs, int n,
                                                int* __restrict__ wtot) {
    __syncthreads();
    int t = threadIdx.x, lane = t & 63, wv = t >> 6;
    int i0 = 2 * t, i1 = i0 + 1;
    int a0 = (i0 < n) ? cnt[i0] : 0;
    int a1 = (i1 < n) ? cnt[i1] : 0;
    int s = a0 + a1, incl = s;
#pragma unroll
    for (int d = 1; d < 64; d <<= 1) {
        int v = __shfl_up(incl, d, 64);
        if (lane >= d) incl += v;
    }
    if (lane == 63) wtot[wv] = incl;
    __syncthreads();
    int woff = 0;
#pragma unroll
    for (int w = 0; w < 16; ++w) { int x = wtot[w]; if (w < wv) woff += x; }
    int excl = woff + incl - s;
    if (i0 < n) lofs[i0] = excl;
    if (i1 < n) lofs[i1] = excl + a0;
    __syncthreads();
}

// K3: binning — counts precomputed; user payload pre-scaled by scl[ic] when USE8
template <bool USE8>
__global__ void __launch_bounds__(1024)
binning_kernel(const int* __restrict__ head, const int* __restrict__ tail,
               const int* __restrict__ etype,
               const int* __restrict__ iu, const int* __restrict__ ic,
               const float* __restrict__ ival, const float* __restrict__ scl,
               const int* __restrict__ cnts_cat, const int* __restrict__ cnts_u0,
               const int* __restrict__ cnts_u1,
               int* __restrict__ cur,
               int* __restrict__ ebinned, unsigned long long* __restrict__ nbinned) {
    __shared__ int scnt[NB_H];
    __shared__ int lofs[NB_H];
    __shared__ int gbase[NB_H];
    __shared__ int wtot[16];
    __shared__ int stage[BIN_CH];
    __shared__ unsigned short sbk[BIN_CH];
    int t = threadIdx.x;
    int hb = blockIdx.x;
    int c0 = hb * BIN_CH;
    int c1 = min(c0 + BIN_CH, E_EDGES);

    // ---- CAT edges ----
    for (int i = t; i < NB_H; i += 1024) scnt[i] = NTL(&cnts_cat[hb * NB_H + i]);
    block_scan_excl(scnt, lofs, NB_H, wtot);
    for (int i = t; i < NB_H; i += 1024) {
        int c = scnt[i];
        gbase[i] = c ? atomicAdd(&cur[i], c) : 0;
    }
    __syncthreads();
    for (int i = t; i < NB_H; i += 1024) scnt[i] = 0;
    __syncthreads();
    for (int e = c0 + t; e < c1; e += 1024) {
        int h = NTL(&head[e]);
        int b = h / HPB;
        int r = atomicAdd(&scnt[b], 1);
        int slot = lofs[b] + r;
        stage[slot] = ((h - b * HPB) << 21) | (NTL(&tail[e]) << 4) | (NTL(&etype[e]) - 1);
        sbk[slot] = (unsigned short)b;
    }
    __syncthreads();
    int cn = c1 - c0;
    for (int s = t; s < cn; s += 1024) {
        int bk = sbk[s];
        ebinned[gbase[bk] + (s - lofs[bk])] = stage[s];
    }

    // ---- USER nnz: two half-chunks ----
    int2* stage2 = (int2*)stage;
    int2* nb2 = (int2*)nbinned;
#pragma unroll 1
    for (int half = 0; half < 2; ++half) {
        int h0 = c0 + half * (BIN_CH / 2);
        int h1 = min(h0 + BIN_CH / 2, E_EDGES);
        const int* crow = half ? cnts_u1 : cnts_u0;
        __syncthreads();
        for (int i = t; i < NB_U; i += 1024) scnt[i] = NTL(&crow[hb * 640 + i]);
        block_scan_excl(scnt, lofs, NB_U, wtot);
        for (int i = t; i < NB_U; i += 1024) {
            int c = scnt[i];
            gbase[i] = c ? atomicAdd(&cur[NB_H + i], c) : 0;
        }
        __syncthreads();
        for (int i = t; i < NB_U; i += 1024) scnt[i] = 0;
        __syncthreads();
        for (int e = h0 + t; e < h1; e += 1024) {
            int u = NTL(&iu[e]);
            int b = u / UPB;
            int r = atomicAdd(&scnt[b], 1);
            int slot = lofs[b] + r;
            int cix = NTL(&ic[e]);
            float v = NTL(&ival[e]);
            if (USE8) v *= scl[cix];
            stage2[slot] = make_int2(((u - b * UPB) << 17) | cix, __float_as_int(v));
            sbk[slot] = (unsigned short)b;
        }
        __syncthreads();
        int hn = h1 - h0;
        for (int s = t; s < hn; s += 1024) {
            int bk = sbk[s];
            nb2[gbase[bk] + (s - lofs[bk])] = stage2[s];
        }
    }
}

// K4: fused agg — blocks [0,NB_H): cat softmax-agg; [NB_H,NB_T): user agg
// int8 rows + f16 normsq (L2-resident tables); NT streaming reads
template <bool USE8>
__global__ void __launch_bounds__(512)
fused_agg(const int* __restrict__ ebinned, const int* __restrict__ hbase,
          const unsigned long long* __restrict__ nbinned, const int* __restrict__ ubase,
          const __half* __restrict__ normsq16, const float* __restrict__ catf,
          const unsigned int* __restrict__ cat8, const float* __restrict__ scl,
          const float* __restrict__ weight,
          float* __restrict__ catagg, float* __restrict__ useragg) {
    __shared__ unsigned long long buf8[CAP8];
    __shared__ float4 wlds4[N_RELM1 * 16];
    __shared__ float hn[HPB * N_RELM1];
    __shared__ int cnt[HPB];
    __shared__ int ofs[HPB + 1];
    __shared__ unsigned int mxu[HPB];
    __shared__ float Zs[HPB];
    const float4* cfr = (const float4*)catf;
    int t = threadIdx.x;
    int wid = t >> 6, lane = t & 63;
    int qlane = lane & 15, qid = lane >> 4;

    if (blockIdx.x < NB_H) {
        int b = blockIdx.x;
        int s0 = hbase[b];
        int n = min(hbase[b + 1] - s0, CAP8);
        for (int i = t; i < N_RELM1 * 16; i += 512)
            wlds4[i] = ((const float4*)weight)[i];
        for (int i = t; i < HPB * N_RELM1; i += 512)
            hn[i] = __half2float(normsq16[(size_t)b * HPB * N_RELM1 + i]);
        for (int i = t; i < HPB; i += 512) { cnt[i] = 0; mxu[i] = 0u; Zs[i] = 0.f; }
        __syncthreads();
        for (int i = t; i < n; i += 512)
            atomicAdd(&cnt[NTL(&ebinned[s0 + i]) >> 21], 1);
        __syncthreads();
        if (wid == 0) {
            int i0 = 2 * lane, i1 = 2 * lane + 1;
            int c0 = (i0 < HPB) ? cnt[i0] : 0;
            int c1 = (i1 < HPB) ? cnt[i1] : 0;
            int s = c0 + c1, incl = s;
#pragma unroll
            for (int d = 1; d < 64; d <<= 1) {
                int v = __shfl_up(incl, d, 64);
                if (lane >= d) incl += v;
            }
            int excl = incl - s;
            if (i0 <= HPB) ofs[i0] = excl;
            if (i1 <= HPB) ofs[i1] = excl + c0;
        }
        __syncthreads();
        for (int i = t; i < HPB; i += 512) cnt[i] = 0;
        __syncthreads();
        for (int i = t; i < n; i += 512) {
            int pk = NTL(&ebinned[s0 + i]);
            int hl = pk >> 21, tj = (pk >> 4) & 0x1FFFF, rj = pk & 15;
            float nt = __half2float(normsq16[(size_t)tj * N_RELM1 + rj]);
            float att = hn[hl * N_RELM1 + rj] * nt;
            int r = atomicAdd(&cnt[hl], 1);
            buf8[ofs[hl] + r] = ((unsigned long long)__float_as_uint(att) << 32) | (unsigned int)pk;
            atomicMax(&mxu[hl], __float_as_uint(att));
        }
        __syncthreads();
        // exp pass: Z += w; store w*scl[tj] (scl hoisted out of gather loop)
        for (int i = t; i < n; i += 512) {
            unsigned long long pay = buf8[i];
            int pk = (int)(unsigned int)pay;
            int hl = pk >> 21;
            float att = __uint_as_float((unsigned int)(pay >> 32));
            float w = __expf(att - __uint_as_float(mxu[hl]));
            float wstore = USE8 ? w * scl[(pk >> 4) & 0x1FFFF] : w;
            ((unsigned int*)buf8)[2 * i + 1] = __float_as_uint(wstore);
            atomicAdd(&Zs[hl], w);
        }
        __syncthreads();
        // quarter-split gather, 4-deep (16 edges/iter)
        for (int hl = wid; hl < HPB; hl += 8) {
            int h = b * HPB + hl;
            int e0 = ofs[hl], e1 = ofs[hl + 1];
            float invZ = (e1 > e0) ? 1.f / Zs[hl] : 0.f;
            float ax = 0.f, ay = 0.f, az = 0.f, aw = 0.f;
            for (int j = e0; j < e1; j += 16) {
#pragma unroll
                for (int k = 0; k < 4; ++k) {
                    int idx = j + k * 4 + qid;
                    bool ok = idx < e1;
                    idx = ok ? idx : e0;
                    unsigned long long pay = buf8[idx];
                    int pk = (int)(unsigned int)pay;
                    float ws = ok ? __uint_as_float((unsigned int)(pay >> 32)) : 0.f;
                    int tj = (pk >> 4) & 0x1FFFF, rj = pk & 15;
                    float4 wl = wlds4[rj * 16 + qlane];
                    if (USE8) {
                        unsigned int uv = cat8[(size_t)tj * 16 + qlane];
                        ax += ws * sb2f(uv, 0)  * wl.x;
                        ay += ws * sb2f(uv, 8)  * wl.y;
                        az += ws * sb2f(uv, 16) * wl.z;
                        aw += ws * sb2f(uv, 24) * wl.w;
                    } else {
                        float4 cv = cfr[(size_t)tj * 16 + qlane];
                        ax += ws * cv.x * wl.x;
                        ay += ws * cv.y * wl.y;
                        az += ws * cv.z * wl.z;
                        aw += ws * cv.w * wl.w;
                    }
                }
            }
            ax += __shfl_xor(ax, 16, 64); ax += __shfl_xor(ax, 32, 64);
            ay += __shfl_xor(ay, 16, 64); ay += __shfl_xor(ay, 32, 64);
            az += __shfl_xor(az, 16, 64); az += __shfl_xor(az, 32, 64);
            aw += __shfl_xor(aw, 16, 64); aw += __shfl_xor(aw, 32, 64);
            if (lane < 16)
                ((float4*)catagg)[(size_t)h * 16 + qlane] =
                    make_float4(ax * invZ, ay * invZ, az * invZ, aw * invZ);
        }
    } else {
        int ub = blockIdx.x - NB_H;
        int s0 = ubase[ub];
        int n = min(ubase[ub + 1] - s0, CAP8);
        for (int i = t; i < UPB; i += 512) cnt[i] = 0;
        __syncthreads();
        for (int i = t; i < n; i += 512)
            atomicAdd(&cnt[((unsigned int)NTL(&nbinned[s0 + i])) >> 17], 1);
        __syncthreads();
        if (wid == 0) {
            int i0 = 2 * lane, i1 = 2 * lane + 1;
            int c0 = (i0 < UPB) ? cnt[i0] : 0;
            int c1 = (i1 < UPB) ? cnt[i1] : 0;
            int s = c0 + c1, incl = s;
#pragma unroll
            for (int d = 1; d < 64; d <<= 1) {
                int v = __shfl_up(incl, d, 64);
                if (lane >= d) incl += v;
            }
            int excl = incl - s;
            if (i0 <= UPB) ofs[i0] = excl;
            if (i1 <= UPB) ofs[i1] = excl + c0;
        }
        __syncthreads();
        for (int i = t; i < UPB; i += 512) cnt[i] = 0;
        __syncthreads();
        for (int i = t; i < n; i += 512) {
            unsigned long long pay = NTL(&nbinned[s0 + i]);
            int ul = ((unsigned int)pay) >> 17;
            int r = atomicAdd(&cnt[ul], 1);
            buf8[ofs[ul] + r] = pay;
        }
        __syncthreads();
        // quarter-split gather, 8-deep (32 edges/iter); payload value pre-scaled
        for (int ul = wid; ul < UPB; ul += 8) {
            int u = ub * UPB + ul;
            int e0 = ofs[ul], e1 = ofs[ul + 1];
            float ax = 0.f, ay = 0.f, az = 0.f, aw = 0.f;
            for (int j = e0; j < e1; j += 32) {
#pragma unroll
                for (int k = 0; k < 8; ++k) {
                    int idx = j + k * 4 + qid;
                    bool ok = idx < e1;
                    idx = ok ? idx : e0;
                    unsigned long long pay = buf8[idx];
                    float vs = ok ? __uint_as_float((unsigned int)(pay >> 32)) : 0.f;
                    int c = (int)((unsigned int)pay & 0x1FFFFu);
                    if (USE8) {
                        unsigned int uv = cat8[(size_t)c * 16 + qlane];
                        ax += vs * sb2f(uv, 0);
                        ay += vs * sb2f(uv, 8);
                        az += vs * sb2f(uv, 16);
                        aw += vs * sb2f(uv, 24);
                    } else {
                        float4 cv = cfr[(size_t)c * 16 + qlane];
                        ax += vs * cv.x;
                        ay += vs * cv.y;
                        az += vs * cv.z;
                        aw += vs * cv.w;
                    }
                }
            }
            ax += __shfl_xor(ax, 16, 64); ax += __shfl_xor(ax, 32, 64);
            ay += __shfl_xor(ay, 16, 64); ay += __shfl_xor(ay, 32, 64);
            az += __shfl_xor(az, 16, 64); az += __shfl_xor(az, 32, 64);
            aw += __shfl_xor(aw, 16, 64); aw += __shfl_xor(aw, 32, 64);
            if (lane < 16) {
                float4 gf = ((float4*)useragg)[(size_t)u * 16 + qlane];
                ((float4*)useragg)[(size_t)u * 16 + qlane] =
                    make_float4(ax * (1.f + gf.x), ay * (1.f + gf.y),
                                az * (1.f + gf.z), aw * (1.f + gf.w));
            }
        }
    }
}

extern "C" void kernel_launch(void* const* d_in, const int* in_sizes, int n_in,
                              void* d_out, int out_size, void* d_ws, size_t ws_size,
                              hipStream_t stream) {
    const float* cat    = (const float*)d_in[0];
    const float* uemb   = (const float*)d_in[1];
    const int*   eidx   = (const int*)d_in[2];
    const int*   etype  = (const int*)d_in[3];
    const int*   iidx   = (const int*)d_in[4];
    const float* ival   = (const float*)d_in[5];
    const float* weight = (const float*)d_in[6];

    float* catagg  = (float*)d_out;
    float* useragg = (float*)d_out + (size_t)N_CAT * DIM;

    // workspace layout (4-byte words); normsq slot reused as f16 (half occupancy)
    int* ws = (int*)d_ws;
    __half* normsq16 = (__half*)ws;                            // 1.5M halves (in 1.5M-word slot)
    int*   ebinned  = ws + 1500000;                            // [1.5M, 3M)
    unsigned long long* nbinned = (unsigned long long*)(ws + 3000000); // [3M, 6M)
    int*   gcnt     = ws + 6000000;                            // 1425
    int*   hbase    = ws + 6001425;                            // 801
    int*   ubase    = ws + 6002226;                            // 626
    int*   cur      = ws + 6002852;                            // 1425
    unsigned int* cat8 = (unsigned int*)(ws + 6004278);        // 1.6M words = 6.4MB int8 table
    float* scl      = (float*)(ws + 6004278 + 1600000);        // 100K floats
    const size_t NEED8 = (size_t)(6004278 + 1600000 + 100000) * 4;
    bool use8 = ws_size >= NEED8;

    // per-chunk count matrices live in the (dead-until-fused_agg) catagg region
    int* dscr     = (int*)d_out;
    int* cnts_cat = dscr;                   // 256*800
    int* cnts_u0  = dscr + 256 * NB_H;      // 256*640
    int* cnts_u1  = cnts_u0 + 256 * 640;    // 256*640

    const int* head = eidx;
    const int* tail = eidx + E_EDGES;
    const int* iu   = iidx;
    const int* ic   = iidx + NNZ_E;

    hipMemsetAsync(gcnt, 0, (size_t)NB_T * sizeof(int), stream);

    if (use8) {
        prep_kernel<true><<<NS_TILES + GT_TILES + BIN_BLKS, 256, 0, stream>>>(
            cat, uemb, weight, head, iu, normsq16, cat8, scl, useragg, gcnt,
            cnts_cat, cnts_u0, cnts_u1);
        bscan_kernel<<<1, 1024, 0, stream>>>(gcnt, hbase, ubase, cur);
        binning_kernel<true><<<BIN_BLKS, 1024, 0, stream>>>(
            head, tail, etype, iu, ic, ival, scl,
            cnts_cat, cnts_u0, cnts_u1, cur, ebinned, nbinned);
        fused_agg<true><<<NB_T, 512, 0, stream>>>(
            ebinned, hbase, nbinned, ubase, normsq16, cat, cat8, scl, weight, catagg, useragg);
    } else {
        prep_kernel<false><<<NS_TILES + GT_TILES + BIN_BLKS, 256, 0, stream>>>(
            cat, uemb, weight, head, iu, normsq16, cat8, scl, useragg, gcnt,
            cnts_cat, cnts_u0, cnts_u1);
        bscan_kernel<<<1, 1024, 0, stream>>>(gcnt, hbase, ubase, cur);
        binning_kernel<false><<<BIN_BLKS, 1024, 0, stream>>>(
            head, tail, etype, iu, ic, ival, scl,
            cnts_cat, cnts_u0, cnts_u1, cur, ebinned, nbinned);
        fused_agg<false><<<NB_T, 512, 0, stream>>>(
            ebinned, hbase, nbinned, ubase, normsq16, cat, cat8, scl, weight, catagg, useragg);
    }
}